// Round 8
// baseline (140.016 us; speedup 1.0000x reference)
//
#include <hip/hip_runtime.h>

typedef _Float16 half8 __attribute__((ext_vector_type(8)));
typedef _Float16 half4_t __attribute__((ext_vector_type(4)));
typedef __fp16 fp16x2 __attribute__((ext_vector_type(2)));
typedef float float4_t __attribute__((ext_vector_type(4)));
typedef float float2_t __attribute__((ext_vector_type(2)));

#define SB 64            // samples per block
#define NT 512           // threads per block (8 waves, 1 m-tile each, 4 n-tiles)
#define RS (SB * 8)      // chunk-row stride in fp16 elems (512)

// d_ws fp16 element offsets (weights, MFMA-chunk-major, pre-scaled)
#define OFF_W1   0       // [128][32] chunk-major, k>=6 zero-padded, x2log2e
#define OFF_W21  4096
#define OFF_W22  20480
#define OFF_WM1  36864
#define OFF_WM2  53248
#define OFF_W4A  69632   // L4 A-frags: chain0=w31 (raw), chain1=w32 x(-log2e)
#define OFF_BIAS 73728   // fp32[640]: b1..bm2, all x2log2e (acc-init values)
#define WS_HELEMS 73728

#define SCL_TANH 2.8853900817779268f   // 2*log2(e)
#define SCL_SIG  -1.4426950408889634f  // -log2(e)

// input already scaled by 2log2e: tanh = 1 - 2/(1+exp2(a))
__device__ __forceinline__ float tanh_pre(float a) {
  float e = __builtin_amdgcn_exp2f(a);
  return fmaf(-2.f, __builtin_amdgcn_rcpf(1.f + e), 1.f);
}
__device__ __forceinline__ half4_t pack4(float v0, float v1, float v2, float v3) {
  fp16x2 lo = __builtin_amdgcn_cvt_pkrtz(v0, v1);
  fp16x2 hi = __builtin_amdgcn_cvt_pkrtz(v2, v3);
  half4_t h;
  h[0] = (_Float16)lo[0]; h[1] = (_Float16)lo[1];
  h[2] = (_Float16)hi[0]; h[3] = (_Float16)hi[1];
  return h;
}

__global__ void prepack(const float* __restrict__ w1, const float* __restrict__ w21,
                        const float* __restrict__ w22, const float* __restrict__ wm1,
                        const float* __restrict__ wm2, const float* __restrict__ w31,
                        const float* __restrict__ w32, const float* __restrict__ b1,
                        const float* __restrict__ b21, const float* __restrict__ b22,
                        const float* __restrict__ bm1, const float* __restrict__ bm2,
                        _Float16* __restrict__ ws) {
  const int stride = gridDim.x * blockDim.x;
  for (int i = blockIdx.x * blockDim.x + threadIdx.x; i < WS_HELEMS; i += stride) {
    float v;
    if (i < OFF_W21) {                       // W1: [128][32] chunk-major, KC=4
      int t = i;
      int j = t & 7, c = t >> 3, l16 = c & 15, t1 = c >> 4;
      int k8 = t1 & 3, mt = t1 >> 2;
      int row = mt * 16 + l16, k = k8 * 8 + j;
      v = (k < 6) ? w1[row * 6 + k] * SCL_TANH : 0.f;
    } else if (i < OFF_W4A) {                // four 128x128 chunk-major, KC=16
      int t = i - OFF_W21;
      int m = t >> 14; t &= 16383;
      const float* src = (m == 0) ? w21 : (m == 1) ? w22 : (m == 2) ? wm1 : wm2;
      int j = t & 7, c = t >> 3, l16 = c & 15, t1 = c >> 4;
      int k8 = t1 & 15, mt = t1 >> 4;
      v = src[(mt * 16 + l16) * 128 + k8 * 8 + j] * SCL_TANH;
    } else {                                 // L4 A-frags, 2 chains
      int t = i - OFF_W4A;
      int j = t & 7, r = t >> 3, l16 = r & 15, q = r >> 4;
      int cc = q & 15, chain = q >> 4;
      int k = cc * 8 + j, m = l16;
      if (chain == 0) v = (m < 3) ? w31[m * 128 + k] : 0.f;
      else            v = (m < 2) ? w32[m * 128 + k] * SCL_SIG : 0.f;
    }
    ws[i] = (_Float16)v;
  }
  float* bws = (float*)(ws + OFF_BIAS);
  for (int i = blockIdx.x * blockDim.x + threadIdx.x; i < 640; i += stride) {
    int layer = i >> 7, idx = i & 127;
    const float* src = (layer == 0) ? b1 : (layer == 1) ? b21
                     : (layer == 2) ? b22 : (layer == 3) ? bm1 : bm2;
    bws[i] = src[idx] * SCL_TANH;
  }
}

// 16-row x 64-sample layer slice from register A-frags; bias folded into acc
// init; tanh fused; chunk-major LDS in/out. 4 independent acc chains (ILP).
__device__ __forceinline__ void layer128(const half8* __restrict__ A, float4_t bv,
                                         const _Float16* __restrict__ inB,
                                         _Float16* __restrict__ outB,
                                         int quad, int l16, int wv) {
  float4_t acc[4];
  acc[0] = bv; acc[1] = bv; acc[2] = bv; acc[3] = bv;
#pragma unroll
  for (int kk = 0; kk < 4; ++kk) {
#pragma unroll
    for (int nt = 0; nt < 4; ++nt) {
      half8 b = *(const half8*)(inB + (kk * 4 + quad) * RS + (nt * 16 + l16) * 8);
      acc[nt] = __builtin_amdgcn_mfma_f32_16x16x32_f16(A[kk], b, acc[nt], 0, 0, 0);
    }
  }
  const int ob = wv * 16 + quad * 4;
  _Float16* base = outB + (ob >> 3) * RS + (ob & 7);
#pragma unroll
  for (int nt = 0; nt < 4; ++nt) {
    const int s = nt * 16 + l16;
    half4_t h = pack4(tanh_pre(acc[nt][0]), tanh_pre(acc[nt][1]),
                      tanh_pre(acc[nt][2]), tanh_pre(acc[nt][3]));
    *(half4_t*)(base + s * 8) = h;
  }
}

// LDS budget: 3 x 16KB = 48KB -> 3 blocks/CU (24 waves/CU static).
// Buffer lifetimes: H: h -> (read L21/L22) -> xm1 out -> (read chain0)
//                   A: x21 -> (read M1)    -> xm2 out -> (read chain1)
//                   B: x22 -> (read M2)
__global__ __launch_bounds__(NT, 6) void bnet_main(
    const float* __restrict__ x, const float* __restrict__ meang,
    const float* __restrict__ stdg, const float* __restrict__ b31,
    const float* __restrict__ b32, const _Float16* __restrict__ ws,
    float* __restrict__ out) {
  __shared__ __align__(16) _Float16 bufH[SB * 128];
  __shared__ __align__(16) _Float16 bufA[SB * 128];
  __shared__ __align__(16) _Float16 bufB[SB * 128];

  const int tid = threadIdx.x;
  const int wv = tid >> 6;          // 0..7 = m-tile
  const int lane = tid & 63;
  const int quad = lane >> 4;
  const int l16 = lane & 15;
  const int s0 = blockIdx.x * SB;
  const float* biasF = (const float*)(ws + OFF_BIAS);
  const int arow = (wv * 16 + quad * 4);   // C rows this lane owns

  // ---- prologue: L1 A-frag + biases, prefetch L21 frags ----
  half8 A1 = *(const half8*)(ws + OFF_W1 + ((wv * 4 + quad) * 16 + l16) * 8);
  float4_t bv1 = *(const float4_t*)(biasF + arow);
  float4_t bv21 = *(const float4_t*)(biasF + 128 + arow);
  float4_t bv22 = *(const float4_t*)(biasF + 256 + arow);
  float4_t bvm1 = *(const float4_t*)(biasF + 384 + arow);
  float4_t bvm2 = *(const float4_t*)(biasF + 512 + arow);
  half8 A21[4];
#pragma unroll
  for (int kk = 0; kk < 4; ++kk)
    A21[kk] = *(const half8*)(ws + OFF_W21 + ((wv * 16 + kk * 4 + quad) * 16 + l16) * 8);

  // ---- L1: B built from global x (K=32 zero-padded), 4 n-tiles -> H ----
  {
    float4_t acc[4];
    acc[0] = bv1; acc[1] = bv1; acc[2] = bv1; acc[3] = bv1;
#pragma unroll
    for (int nt = 0; nt < 4; ++nt) {
      half8 v;
#pragma unroll
      for (int j = 0; j < 8; ++j) v[j] = (_Float16)0.f;
      if (quad == 0) {
        const float* xp = x + (size_t)(s0 + nt * 16 + l16) * 6;
        float2_t e0 = *(const float2_t*)(xp);
        float2_t e1 = *(const float2_t*)(xp + 2);
        float2_t e2 = *(const float2_t*)(xp + 4);
        v[0] = (_Float16)e0[0]; v[1] = (_Float16)e0[1];
        v[2] = (_Float16)e1[0]; v[3] = (_Float16)e1[1];
        v[4] = (_Float16)e2[0]; v[5] = (_Float16)e2[1];
      }
      acc[nt] = __builtin_amdgcn_mfma_f32_16x16x32_f16(A1, v, acc[nt], 0, 0, 0);
    }
    _Float16* base = bufH + (arow >> 3) * RS + (arow & 7);
#pragma unroll
    for (int nt = 0; nt < 4; ++nt) {
      const int s = nt * 16 + l16;
      half4_t h = pack4(tanh_pre(acc[nt][0]), tanh_pre(acc[nt][1]),
                        tanh_pre(acc[nt][2]), tanh_pre(acc[nt][3]));
      *(half4_t*)(base + s * 8) = h;
    }
  }
  half8 A22[4];   // prefetch L22 (overlaps barrier drain)
#pragma unroll
  for (int kk = 0; kk < 4; ++kk)
    A22[kk] = *(const half8*)(ws + OFF_W22 + ((wv * 16 + kk * 4 + quad) * 16 + l16) * 8);
  __syncthreads();                                   // b1

  layer128(A21, bv21, bufH, bufA, quad, l16, wv);    // x21: H -> A
  half8 AM1[4];                                      // prefetch LM1
#pragma unroll
  for (int kk = 0; kk < 4; ++kk)
    AM1[kk] = *(const half8*)(ws + OFF_WM1 + ((wv * 16 + kk * 4 + quad) * 16 + l16) * 8);
  layer128(A22, bv22, bufH, bufB, quad, l16, wv);    // x22: H -> B
  __syncthreads();                                   // b2

  layer128(AM1, bvm1, bufA, bufH, quad, l16, wv);    // xm1: A -> H
  half8 AM2[4];                                      // prefetch LM2
#pragma unroll
  for (int kk = 0; kk < 4; ++kk)
    AM2[kk] = *(const half8*)(ws + OFF_WM2 + ((wv * 16 + kk * 4 + quad) * 16 + l16) * 8);
  half8 A4[2][4];                                    // prefetch L4 (waves 0-3)
  if (wv < 4) {
#pragma unroll
    for (int c = 0; c < 2; ++c)
#pragma unroll
      for (int kk = 0; kk < 4; ++kk)
        A4[c][kk] = *(const half8*)(ws + OFF_W4A +
                                    ((c * 16 + kk * 4 + quad) * 16 + l16) * 8);
  }
  __syncthreads();                                   // b3

  layer128(AM2, bvm2, bufB, bufA, quad, l16, wv);    // xm2: B -> A
  // L4 chain0 (u-linear term): reads xm1 in H, stable since b3. Waves 0-3.
  float4_t c0 = (float4_t){0.f, 0.f, 0.f, 0.f};
  if (wv < 4) {
    if (quad == 0) { c0[0] = b31[0]; c0[1] = b31[1]; c0[2] = b31[2]; }
    const int nt = wv;
#pragma unroll
    for (int kk = 0; kk < 4; ++kk) {
      half8 bh = *(const half8*)(bufH + (kk * 4 + quad) * RS + (nt * 16 + l16) * 8);
      c0 = __builtin_amdgcn_mfma_f32_16x16x32_f16(A4[0][kk], bh, c0, 0, 0, 0);
    }
  }
  __syncthreads();                                   // b4

  // ---- L4 chain1 + QP epilogue: waves 0-3, one 16-sample n-tile each ----
  if (wv < 4) {
    const int nt = wv;
    float4_t c1 = (float4_t){0.f, 0.f, 0.f, 0.f};
    if (quad == 0) { c1[0] = b32[0] * SCL_SIG; c1[1] = b32[1] * SCL_SIG; }
#pragma unroll
    for (int kk = 0; kk < 4; ++kk) {
      half8 bc = *(const half8*)(bufA + (kk * 4 + quad) * RS + (nt * 16 + l16) * 8);
      c1 = __builtin_amdgcn_mfma_f32_16x16x32_f16(A4[1][kk], bc, c1, 0, 0, 0);
    }
    if (quad == 0) {   // rows 0..3 live in lanes 0-15, regs 0-3
      const int s = nt * 16 + l16;
      float u0 = -c0[0];
      float u1 = -c0[1];
      float u2 = -c0[2];
      float p0 = 4.f * __builtin_amdgcn_rcpf(1.f + __builtin_amdgcn_exp2f(c1[0]));
      float p1 = 4.f * __builtin_amdgcn_rcpf(1.f + __builtin_amdgcn_exp2f(c1[1]));
      const float m0 = meang[0], m1 = meang[1], m2 = meang[2];
      const float m3 = meang[3], m4 = meang[4], m5 = meang[5];
      const float sd0 = stdg[0], sd1 = stdg[1], sd2 = stdg[2];
      const float sd3 = stdg[3], sd4 = stdg[4], sd5 = stdg[5];
      const float* xp = x + (size_t)(s0 + s) * 6;
      float2_t e0 = *(const float2_t*)(xp);
      float2_t e1 = *(const float2_t*)(xp + 2);
      float2_t e2 = *(const float2_t*)(xp + 4);
      float px = e0[0] * sd0 + m0, vx = e0[1] * sd1 + m1;
      float py = e1[0] * sd2 + m2, vy = e1[1] * sd3 + m3;
      float pz = e2[0] * sd4 + m4, vz = e2[1] * sd5 + m5;
      float dx = px - 10.f, dy = py - 10.f, dz = pz - 9.f;
      float dx2 = dx * dx, dy2 = dy * dy, dz2 = dz * dz;
      float dx3 = dx2 * dx, dy3 = dy2 * dy, dz3 = dz2 * dz;
      float barrier = dx3 * dx + dy3 * dy + dz3 * dz - 2401.f;  // R^4
      float bdot = 4.f * (dx3 * vx + dy3 * vy + dz3 * vz);
      float Lf2b = 12.f * (dx2 * vx * vx + dy2 * vy * vy + dz2 * vz * vz);
      float g0 = -4.f * dx3, g1 = -4.f * dy3, g2 = -4.f * dz3;
      float hv = Lf2b + (p0 + p1) * bdot + p0 * p1 * barrier;
      float Gu = g0 * u0 + g1 * u1 + g2 * u2;
      float GG = g0 * g0 + g1 * g1 + g2 * g2;
      float lam = fmaxf(Gu - hv, 0.f) / GG;
      float* op = out + (size_t)(s0 + s) * 3;
      op[0] = u0 - lam * g0;
      op[1] = u1 - lam * g1;
      op[2] = u2 - lam * g2;
    }
  }
}

extern "C" void kernel_launch(void* const* d_in, const int* in_sizes, int n_in,
                              void* d_out, int out_size, void* d_ws, size_t ws_size,
                              hipStream_t stream) {
  const float* x    = (const float*)d_in[0];
  const float* mean = (const float*)d_in[1];
  const float* stdv = (const float*)d_in[2];
  const float* w1   = (const float*)d_in[3];
  const float* b1   = (const float*)d_in[4];
  const float* w21  = (const float*)d_in[5];
  const float* b21  = (const float*)d_in[6];
  const float* w22  = (const float*)d_in[7];
  const float* b22  = (const float*)d_in[8];
  const float* wm1  = (const float*)d_in[9];
  const float* bm1  = (const float*)d_in[10];
  const float* wm2  = (const float*)d_in[11];
  const float* bm2  = (const float*)d_in[12];
  const float* w31  = (const float*)d_in[13];
  const float* b31  = (const float*)d_in[14];
  const float* w32  = (const float*)d_in[15];
  const float* b32  = (const float*)d_in[16];
  _Float16* ws = (_Float16*)d_ws;
  float* out = (float*)d_out;
  const int batch = in_sizes[0] / 6;

  hipLaunchKernelGGL(prepack, dim3(96), dim3(256), 0, stream,
                     w1, w21, w22, wm1, wm2, w31, w32,
                     b1, b21, b22, bm1, bm2, ws);
  hipLaunchKernelGGL(bnet_main, dim3(batch / SB), dim3(NT), 0, stream,
                     x, mean, stdv, b31, b32, (const _Float16*)ws, out);
}

// Round 9
// 120.863 us; speedup vs baseline: 1.1585x; 1.1585x over previous
//
#include <hip/hip_runtime.h>

typedef _Float16 half8 __attribute__((ext_vector_type(8)));
typedef _Float16 half4_t __attribute__((ext_vector_type(4)));
typedef __fp16 fp16x2 __attribute__((ext_vector_type(2)));
typedef float float4_t __attribute__((ext_vector_type(4)));
typedef float float2_t __attribute__((ext_vector_type(2)));

#define SB 64            // samples per block
#define NT 512           // threads per block (8 waves, 1 m-tile each, 4 n-tiles)
#define RS (SB * 8)      // chunk-row stride in fp16 elems (512)

// d_ws fp16 element offsets (weights, MFMA-chunk-major, pre-scaled)
#define OFF_W1   0       // [128][32] chunk-major, k>=6 zero-padded, x2log2e
#define OFF_W21  4096
#define OFF_W22  20480
#define OFF_WM1  36864
#define OFF_WM2  53248
#define OFF_W4A  69632   // L4 A-frags: chain0=w31 (raw), chain1=w32 x(-log2e)
#define OFF_BIAS 73728   // fp32[640]: b1..bm2, all x2log2e (acc-init values)
#define WS_HELEMS 73728

#define SCL_TANH 2.8853900817779268f   // 2*log2(e)
#define SCL_SIG  -1.4426950408889634f  // -log2(e)

// input already scaled by 2log2e: tanh = 1 - 2/(1+exp2(a))
__device__ __forceinline__ float tanh_pre(float a) {
  float e = __builtin_amdgcn_exp2f(a);
  return fmaf(-2.f, __builtin_amdgcn_rcpf(1.f + e), 1.f);
}
__device__ __forceinline__ half4_t pack4(float v0, float v1, float v2, float v3) {
  fp16x2 lo = __builtin_amdgcn_cvt_pkrtz(v0, v1);
  fp16x2 hi = __builtin_amdgcn_cvt_pkrtz(v2, v3);
  half4_t h;
  h[0] = (_Float16)lo[0]; h[1] = (_Float16)lo[1];
  h[2] = (_Float16)hi[0]; h[3] = (_Float16)hi[1];
  return h;
}

__global__ void prepack(const float* __restrict__ w1, const float* __restrict__ w21,
                        const float* __restrict__ w22, const float* __restrict__ wm1,
                        const float* __restrict__ wm2, const float* __restrict__ w31,
                        const float* __restrict__ w32, const float* __restrict__ b1,
                        const float* __restrict__ b21, const float* __restrict__ b22,
                        const float* __restrict__ bm1, const float* __restrict__ bm2,
                        _Float16* __restrict__ ws) {
  const int stride = gridDim.x * blockDim.x;
  for (int i = blockIdx.x * blockDim.x + threadIdx.x; i < WS_HELEMS; i += stride) {
    float v;
    if (i < OFF_W21) {                       // W1: [128][32] chunk-major, KC=4
      int t = i;
      int j = t & 7, c = t >> 3, l16 = c & 15, t1 = c >> 4;
      int k8 = t1 & 3, mt = t1 >> 2;
      int row = mt * 16 + l16, k = k8 * 8 + j;
      v = (k < 6) ? w1[row * 6 + k] * SCL_TANH : 0.f;
    } else if (i < OFF_W4A) {                // four 128x128 chunk-major, KC=16
      int t = i - OFF_W21;
      int m = t >> 14; t &= 16383;
      const float* src = (m == 0) ? w21 : (m == 1) ? w22 : (m == 2) ? wm1 : wm2;
      int j = t & 7, c = t >> 3, l16 = c & 15, t1 = c >> 4;
      int k8 = t1 & 15, mt = t1 >> 4;
      v = src[(mt * 16 + l16) * 128 + k8 * 8 + j] * SCL_TANH;
    } else {                                 // L4 A-frags, 2 chains
      int t = i - OFF_W4A;
      int j = t & 7, r = t >> 3, l16 = r & 15, q = r >> 4;
      int cc = q & 15, chain = q >> 4;
      int k = cc * 8 + j, m = l16;
      if (chain == 0) v = (m < 3) ? w31[m * 128 + k] : 0.f;
      else            v = (m < 2) ? w32[m * 128 + k] * SCL_SIG : 0.f;
    }
    ws[i] = (_Float16)v;
  }
  float* bws = (float*)(ws + OFF_BIAS);
  for (int i = blockIdx.x * blockDim.x + threadIdx.x; i < 640; i += stride) {
    int layer = i >> 7, idx = i & 127;
    const float* src = (layer == 0) ? b1 : (layer == 1) ? b21
                     : (layer == 2) ? b22 : (layer == 3) ? bm1 : bm2;
    bws[i] = src[idx] * SCL_TANH;
  }
}

// 16-row x 64-sample layer slice from register A-frags; bias folded into acc
// init; tanh fused; chunk-major LDS in/out. 4 independent acc chains (ILP).
__device__ __forceinline__ void layer128(const half8* __restrict__ A, float4_t bv,
                                         const _Float16* __restrict__ inB,
                                         _Float16* __restrict__ outB,
                                         int quad, int l16, int wv) {
  float4_t acc[4];
  acc[0] = bv; acc[1] = bv; acc[2] = bv; acc[3] = bv;
#pragma unroll
  for (int kk = 0; kk < 4; ++kk) {
#pragma unroll
    for (int nt = 0; nt < 4; ++nt) {
      half8 b = *(const half8*)(inB + (kk * 4 + quad) * RS + (nt * 16 + l16) * 8);
      acc[nt] = __builtin_amdgcn_mfma_f32_16x16x32_f16(A[kk], b, acc[nt], 0, 0, 0);
    }
  }
  const int ob = wv * 16 + quad * 4;
  _Float16* base = outB + (ob >> 3) * RS + (ob & 7);
#pragma unroll
  for (int nt = 0; nt < 4; ++nt) {
    const int s = nt * 16 + l16;
    half4_t h = pack4(tanh_pre(acc[nt][0]), tanh_pre(acc[nt][1]),
                      tanh_pre(acc[nt][2]), tanh_pre(acc[nt][3]));
    *(half4_t*)(base + s * 8) = h;
  }
}

// LDS budget: 3 x 16KB = 48KB -> 3 blocks/CU (24 waves/CU static).
// __launch_bounds__(512,4): VGPR cap 128 — r8's (512,6) cap of 85 forced
// scratch spill (FETCH 53MB / WRITE 112MB); occupancy stays LDS-limited.
__global__ __launch_bounds__(NT, 4) void bnet_main(
    const float* __restrict__ x, const float* __restrict__ meang,
    const float* __restrict__ stdg, const float* __restrict__ b31,
    const float* __restrict__ b32, const _Float16* __restrict__ ws,
    float* __restrict__ out) {
  __shared__ __align__(16) _Float16 bufH[SB * 128];
  __shared__ __align__(16) _Float16 bufA[SB * 128];
  __shared__ __align__(16) _Float16 bufB[SB * 128];

  const int tid = threadIdx.x;
  const int wv = tid >> 6;          // 0..7 = m-tile
  const int lane = tid & 63;
  const int quad = lane >> 4;
  const int l16 = lane & 15;
  const int s0 = blockIdx.x * SB;
  const float* biasF = (const float*)(ws + OFF_BIAS);
  const int arow = (wv * 16 + quad * 4);   // C rows this lane owns

  // ---- prologue: L1 A-frag + biases, prefetch L21 frags ----
  half8 A1 = *(const half8*)(ws + OFF_W1 + ((wv * 4 + quad) * 16 + l16) * 8);
  float4_t bv1 = *(const float4_t*)(biasF + arow);
  float4_t bv21 = *(const float4_t*)(biasF + 128 + arow);
  float4_t bv22 = *(const float4_t*)(biasF + 256 + arow);
  float4_t bvm1 = *(const float4_t*)(biasF + 384 + arow);
  float4_t bvm2 = *(const float4_t*)(biasF + 512 + arow);
  half8 A21[4];
#pragma unroll
  for (int kk = 0; kk < 4; ++kk)
    A21[kk] = *(const half8*)(ws + OFF_W21 + ((wv * 16 + kk * 4 + quad) * 16 + l16) * 8);

  // ---- L1: B built from global x (K=32 zero-padded), 4 n-tiles -> H ----
  {
    float4_t acc[4];
    acc[0] = bv1; acc[1] = bv1; acc[2] = bv1; acc[3] = bv1;
#pragma unroll
    for (int nt = 0; nt < 4; ++nt) {
      half8 v;
#pragma unroll
      for (int j = 0; j < 8; ++j) v[j] = (_Float16)0.f;
      if (quad == 0) {
        const float* xp = x + (size_t)(s0 + nt * 16 + l16) * 6;
        float2_t e0 = *(const float2_t*)(xp);
        float2_t e1 = *(const float2_t*)(xp + 2);
        float2_t e2 = *(const float2_t*)(xp + 4);
        v[0] = (_Float16)e0[0]; v[1] = (_Float16)e0[1];
        v[2] = (_Float16)e1[0]; v[3] = (_Float16)e1[1];
        v[4] = (_Float16)e2[0]; v[5] = (_Float16)e2[1];
      }
      acc[nt] = __builtin_amdgcn_mfma_f32_16x16x32_f16(A1, v, acc[nt], 0, 0, 0);
    }
    _Float16* base = bufH + (arow >> 3) * RS + (arow & 7);
#pragma unroll
    for (int nt = 0; nt < 4; ++nt) {
      const int s = nt * 16 + l16;
      half4_t h = pack4(tanh_pre(acc[nt][0]), tanh_pre(acc[nt][1]),
                        tanh_pre(acc[nt][2]), tanh_pre(acc[nt][3]));
      *(half4_t*)(base + s * 8) = h;
    }
  }
  half8 A22[4];   // prefetch L22 (overlaps barrier drain)
#pragma unroll
  for (int kk = 0; kk < 4; ++kk)
    A22[kk] = *(const half8*)(ws + OFF_W22 + ((wv * 16 + kk * 4 + quad) * 16 + l16) * 8);
  __syncthreads();                                   // b1

  layer128(A21, bv21, bufH, bufA, quad, l16, wv);    // x21: H -> A
  half8 AM1[4];                                      // prefetch LM1
#pragma unroll
  for (int kk = 0; kk < 4; ++kk)
    AM1[kk] = *(const half8*)(ws + OFF_WM1 + ((wv * 16 + kk * 4 + quad) * 16 + l16) * 8);
  layer128(A22, bv22, bufH, bufB, quad, l16, wv);    // x22: H -> B
  __syncthreads();                                   // b2

  layer128(AM1, bvm1, bufA, bufH, quad, l16, wv);    // xm1: A -> H
  half8 AM2[4];                                      // prefetch LM2
#pragma unroll
  for (int kk = 0; kk < 4; ++kk)
    AM2[kk] = *(const half8*)(ws + OFF_WM2 + ((wv * 16 + kk * 4 + quad) * 16 + l16) * 8);
  half8 A4[2][4];                                    // prefetch L4 (waves 0-3)
  if (wv < 4) {
#pragma unroll
    for (int c = 0; c < 2; ++c)
#pragma unroll
      for (int kk = 0; kk < 4; ++kk)
        A4[c][kk] = *(const half8*)(ws + OFF_W4A +
                                    ((c * 16 + kk * 4 + quad) * 16 + l16) * 8);
  }
  __syncthreads();                                   // b3

  layer128(AM2, bvm2, bufB, bufA, quad, l16, wv);    // xm2: B -> A
  // L4 chain0 (u-linear term): reads xm1 in H, stable since b3. Waves 0-3.
  float4_t c0 = (float4_t){0.f, 0.f, 0.f, 0.f};
  if (wv < 4) {
    if (quad == 0) { c0[0] = b31[0]; c0[1] = b31[1]; c0[2] = b31[2]; }
    const int nt = wv;
#pragma unroll
    for (int kk = 0; kk < 4; ++kk) {
      half8 bh = *(const half8*)(bufH + (kk * 4 + quad) * RS + (nt * 16 + l16) * 8);
      c0 = __builtin_amdgcn_mfma_f32_16x16x32_f16(A4[0][kk], bh, c0, 0, 0, 0);
    }
  }
  __syncthreads();                                   // b4

  // ---- L4 chain1 + QP epilogue: waves 0-3, one 16-sample n-tile each ----
  if (wv < 4) {
    const int nt = wv;
    float4_t c1 = (float4_t){0.f, 0.f, 0.f, 0.f};
    if (quad == 0) { c1[0] = b32[0] * SCL_SIG; c1[1] = b32[1] * SCL_SIG; }
#pragma unroll
    for (int kk = 0; kk < 4; ++kk) {
      half8 bc = *(const half8*)(bufA + (kk * 4 + quad) * RS + (nt * 16 + l16) * 8);
      c1 = __builtin_amdgcn_mfma_f32_16x16x32_f16(A4[1][kk], bc, c1, 0, 0, 0);
    }
    if (quad == 0) {   // rows 0..3 live in lanes 0-15, regs 0-3
      const int s = nt * 16 + l16;
      float u0 = -c0[0];
      float u1 = -c0[1];
      float u2 = -c0[2];
      float p0 = 4.f * __builtin_amdgcn_rcpf(1.f + __builtin_amdgcn_exp2f(c1[0]));
      float p1 = 4.f * __builtin_amdgcn_rcpf(1.f + __builtin_amdgcn_exp2f(c1[1]));
      const float m0 = meang[0], m1 = meang[1], m2 = meang[2];
      const float m3 = meang[3], m4 = meang[4], m5 = meang[5];
      const float sd0 = stdg[0], sd1 = stdg[1], sd2 = stdg[2];
      const float sd3 = stdg[3], sd4 = stdg[4], sd5 = stdg[5];
      const float* xp = x + (size_t)(s0 + s) * 6;
      float2_t e0 = *(const float2_t*)(xp);
      float2_t e1 = *(const float2_t*)(xp + 2);
      float2_t e2 = *(const float2_t*)(xp + 4);
      float px = e0[0] * sd0 + m0, vx = e0[1] * sd1 + m1;
      float py = e1[0] * sd2 + m2, vy = e1[1] * sd3 + m3;
      float pz = e2[0] * sd4 + m4, vz = e2[1] * sd5 + m5;
      float dx = px - 10.f, dy = py - 10.f, dz = pz - 9.f;
      float dx2 = dx * dx, dy2 = dy * dy, dz2 = dz * dz;
      float dx3 = dx2 * dx, dy3 = dy2 * dy, dz3 = dz2 * dz;
      float barrier = dx3 * dx + dy3 * dy + dz3 * dz - 2401.f;  // R^4
      float bdot = 4.f * (dx3 * vx + dy3 * vy + dz3 * vz);
      float Lf2b = 12.f * (dx2 * vx * vx + dy2 * vy * vy + dz2 * vz * vz);
      float g0 = -4.f * dx3, g1 = -4.f * dy3, g2 = -4.f * dz3;
      float hv = Lf2b + (p0 + p1) * bdot + p0 * p1 * barrier;
      float Gu = g0 * u0 + g1 * u1 + g2 * u2;
      float GG = g0 * g0 + g1 * g1 + g2 * g2;
      float lam = fmaxf(Gu - hv, 0.f) / GG;
      float* op = out + (size_t)(s0 + s) * 3;
      op[0] = u0 - lam * g0;
      op[1] = u1 - lam * g1;
      op[2] = u2 - lam * g2;
    }
  }
}

extern "C" void kernel_launch(void* const* d_in, const int* in_sizes, int n_in,
                              void* d_out, int out_size, void* d_ws, size_t ws_size,
                              hipStream_t stream) {
  const float* x    = (const float*)d_in[0];
  const float* mean = (const float*)d_in[1];
  const float* stdv = (const float*)d_in[2];
  const float* w1   = (const float*)d_in[3];
  const float* b1   = (const float*)d_in[4];
  const float* w21  = (const float*)d_in[5];
  const float* b21  = (const float*)d_in[6];
  const float* w22  = (const float*)d_in[7];
  const float* b22  = (const float*)d_in[8];
  const float* wm1  = (const float*)d_in[9];
  const float* bm1  = (const float*)d_in[10];
  const float* wm2  = (const float*)d_in[11];
  const float* bm2  = (const float*)d_in[12];
  const float* w31  = (const float*)d_in[13];
  const float* b31  = (const float*)d_in[14];
  const float* w32  = (const float*)d_in[15];
  const float* b32  = (const float*)d_in[16];
  _Float16* ws = (_Float16*)d_ws;
  float* out = (float*)d_out;
  const int batch = in_sizes[0] / 6;

  hipLaunchKernelGGL(prepack, dim3(96), dim3(256), 0, stream,
                     w1, w21, w22, wm1, wm2, w31, w32,
                     b1, b21, b22, bm1, bm2, ws);
  hipLaunchKernelGGL(bnet_main, dim3(batch / SB), dim3(NT), 0, stream,
                     x, mean, stdv, b31, b32, (const _Float16*)ws, out);
}